// Round 1
// baseline (1547.130 us; speedup 1.0000x reference)
//
#include <hip/hip_runtime.h>

// Problem constants
constexpr int Bc = 32, Sc = 512, Dc = 768, Mc = 32, Tc = 30;
constexpr int Hc = 12, DFFc = 3072, Lc = 4, Ec = 100000, HDc = 64;
constexpr int TOK = Bc * Mc; // 1024 token rows

typedef float floatx4 __attribute__((ext_vector_type(4)));
typedef __bf16 bfrag8 __attribute__((ext_vector_type(8)));
typedef unsigned short usx8 __attribute__((ext_vector_type(8)));
typedef unsigned short usx4 __attribute__((ext_vector_type(4)));

__device__ __forceinline__ unsigned short f32_to_bf16(float f) {
    unsigned int u = __float_as_uint(f);
    unsigned int r = (u + 0x7FFFu + ((u >> 16) & 1u)) >> 16; // RNE
    return (unsigned short)r;
}

// ---------------------------------------------------------------- cvt f32->bf16
__global__ __launch_bounds__(256)
void cvt_kernel(const float* __restrict__ src, unsigned short* __restrict__ dst, int n4) {
    int stride = gridDim.x * 256;
    for (int i = blockIdx.x * 256 + threadIdx.x; i < n4; i += stride) {
        floatx4 v = *(const floatx4*)(src + 4 * (size_t)i);
        usx4 o;
        #pragma unroll
        for (int j = 0; j < 4; ++j) o[j] = f32_to_bf16(v[j]);
        *(usx4*)(dst + 4 * (size_t)i) = o;
    }
}

// ---------------------------------------------------------------- mention pool
__global__ __launch_bounds__(256)
void pool_kernel(const float* __restrict__ lhs, const float* __restrict__ attn_w,
                 const int* __restrict__ pos, const int* __restrict__ emask,
                 float* __restrict__ x0) {
    const int bm = blockIdx.x;          // b*32+m
    const int b = bm >> 5;
    const int tid = threadIdx.x;
    __shared__ float s_logit[32];
    __shared__ float s_w[32];
    __shared__ int s_valid[32];

    if (tid == 0) {
        int em = emask[bm];
        int ok = 1;
        for (int t = 0; t < Tc; ++t) {
            if (pos[bm * Tc + t] == -1) ok = 0;
            s_valid[t] = (ok && em) ? 1 : 0;
        }
    }
    __syncthreads();

    const int wid = tid >> 6, lane = tid & 63;
    for (int t = wid; t < Tc; t += 4) {
        float p = 0.f;
        const float* row = lhs + ((size_t)b * Sc + t) * Dc;
        for (int d = lane; d < Dc; d += 64) p += row[d] * attn_w[d];
        #pragma unroll
        for (int off = 32; off > 0; off >>= 1) p += __shfl_down(p, off);
        if (lane == 0) s_logit[t] = s_valid[t] ? p : 0.0f;  // attn_b cancels in softmax
    }
    __syncthreads();
    if (tid == 0) {
        float mx = -1e30f;
        for (int t = 0; t < Tc; ++t) mx = fmaxf(mx, s_logit[t]);
        float sum = 0.f;
        for (int t = 0; t < Tc; ++t) { float e = expf(s_logit[t] - mx); s_w[t] = e; sum += e; }
        float inv = 1.0f / sum;
        for (int t = 0; t < Tc; ++t) s_w[t] = s_valid[t] ? s_w[t] * inv : 0.0f;
    }
    __syncthreads();
    for (int d = tid; d < Dc; d += 256) {
        float acc = 0.f;
        for (int t = 0; t < Tc; ++t) acc += s_w[t] * lhs[((size_t)b * Sc + t) * Dc + d];
        x0[(size_t)bm * Dc + d] = acc;
    }
}

// ---------------------------------------------------------------- GEMM  C = A @ B^T + bias (opt relu)
// A: f32 [M,K]; B: bf16-bits [N,K]; C: f32 [M,N].  M multiple of BM.
template <int BM, int BN, int WM, int WN>
__global__ __launch_bounds__(256)
void gemm_bf16_kernel(const float* __restrict__ A, const unsigned short* __restrict__ B,
                      const float* __restrict__ bias, float* __restrict__ C,
                      int M, int N, int K, int relu) {
    constexpr int BK = 64;
    constexpr int LK = BK + 8;  // padded LDS row stride (bf16): 144 B -> 2-way bank alias (free)
    __shared__ unsigned short lA[BM * LK];
    __shared__ unsigned short lB[BN * LK];

    const int tid = threadIdx.x;
    const int bm0 = blockIdx.y * BM;
    const int bn0 = blockIdx.x * BN;

    const int wid = tid >> 6;
    const int lane = tid & 63;
    const int quad = lane >> 4;
    const int l16 = lane & 15;
    const int wr = (wid >> 1) * (WM * 16);
    const int wc = (wid & 1) * (WN * 16);

    const int tr = tid >> 3;         // 0..31
    const int tk = (tid & 7) * 8;    // 0..56

    floatx4 acc[WM][WN] = {};

    for (int k0 = 0; k0 < K; k0 += BK) {
        const int gk0 = k0 + tk;
        // stage A (f32 -> bf16)
        for (int r = tr; r < BM; r += 32) {
            const int grow = bm0 + r;
            const float* ap = A + (size_t)grow * K + gk0;
            usx8 t8;
            if (gk0 + 8 <= K) {
                floatx4 u0 = *(const floatx4*)(ap);
                floatx4 u1 = *(const floatx4*)(ap + 4);
                #pragma unroll
                for (int j = 0; j < 4; ++j) { t8[j] = f32_to_bf16(u0[j]); t8[4 + j] = f32_to_bf16(u1[j]); }
            } else {
                #pragma unroll
                for (int j = 0; j < 8; ++j) {
                    int gk = gk0 + j;
                    float v = (gk < K) ? ap[j] : 0.0f;
                    t8[j] = f32_to_bf16(v);
                }
            }
            *(usx8*)(&lA[r * LK + tk]) = t8;
        }
        // stage B (bf16 bits)
        for (int r = tr; r < BN; r += 32) {
            const int gn = bn0 + r;
            usx8 t8 = (usx8)0;
            if (gn < N) {
                const unsigned short* bp = B + (size_t)gn * K + gk0;
                if (((K & 7) == 0) && (gk0 + 8 <= K)) {
                    t8 = *(const usx8*)(bp);
                } else {
                    #pragma unroll
                    for (int j = 0; j < 8; ++j) {
                        int gk = gk0 + j;
                        if (gk < K) t8[j] = bp[j];
                    }
                }
            }
            *(usx8*)(&lB[r * LK + tk]) = t8;
        }
        __syncthreads();
        #pragma unroll
        for (int kk = 0; kk < BK; kk += 32) {
            bfrag8 af[WM], bfr[WN];
            #pragma unroll
            for (int i = 0; i < WM; ++i)
                af[i] = *(const bfrag8*)(&lA[(wr + i * 16 + l16) * LK + kk + quad * 8]);
            #pragma unroll
            for (int j = 0; j < WN; ++j)
                bfr[j] = *(const bfrag8*)(&lB[(wc + j * 16 + l16) * LK + kk + quad * 8]);
            #pragma unroll
            for (int i = 0; i < WM; ++i)
                #pragma unroll
                for (int j = 0; j < WN; ++j)
                    acc[i][j] = __builtin_amdgcn_mfma_f32_16x16x32_bf16(af[i], bfr[j], acc[i][j], 0, 0, 0);
        }
        __syncthreads();
    }

    #pragma unroll
    for (int i = 0; i < WM; ++i) {
        #pragma unroll
        for (int j = 0; j < WN; ++j) {
            const int col = bn0 + wc + j * 16 + l16;
            if (col < N) {
                const int row0 = bm0 + wr + i * 16 + quad * 4;
                const float bv = bias ? bias[col] : 0.0f;
                #pragma unroll
                for (int r = 0; r < 4; ++r) {
                    float v = acc[i][j][r] + bv;
                    if (relu) v = fmaxf(v, 0.0f);
                    C[(size_t)(row0 + r) * N + col] = v;
                }
            }
        }
    }
}

// ---------------------------------------------------------------- attention (one block per (b,h))
__global__ __launch_bounds__(256)
void attn_kernel(const float* __restrict__ qkv, float* __restrict__ out) {
    const int bh = blockIdx.x;
    const int b = bh / Hc, h = bh % Hc;
    const int tid = threadIdx.x;
    __shared__ float sQ[32][65];
    __shared__ float sK[32][65];
    __shared__ float sV[32][65];
    __shared__ float sS[32][33];

    const int m = tid >> 3;
    const int c0 = (tid & 7) * 8;
    {
        const size_t rbase = ((size_t)(b * 32 + m)) * (3 * Dc);
        #pragma unroll
        for (int j = 0; j < 8; ++j) {
            sQ[m][c0 + j] = qkv[rbase + h * HDc + c0 + j];
            sK[m][c0 + j] = qkv[rbase + Dc + h * HDc + c0 + j];
            sV[m][c0 + j] = qkv[rbase + 2 * Dc + h * HDc + c0 + j];
        }
    }
    __syncthreads();

    #pragma unroll
    for (int u = 0; u < 4; ++u) {
        const int e = tid * 4 + u;
        const int q = e >> 5, k = e & 31;
        float s = 0.f;
        #pragma unroll
        for (int d = 0; d < HDc; ++d) s += sQ[q][d] * sK[k][d];
        sS[q][k] = s * 0.125f;
    }
    __syncthreads();
    if (tid < 32) {
        float mx = -1e30f;
        for (int k = 0; k < 32; ++k) mx = fmaxf(mx, sS[tid][k]);
        float sum = 0.f;
        for (int k = 0; k < 32; ++k) { float e = expf(sS[tid][k] - mx); sS[tid][k] = e; sum += e; }
        const float inv = 1.0f / sum;
        for (int k = 0; k < 32; ++k) sS[tid][k] *= inv;
    }
    __syncthreads();
    float o[8] = {};
    for (int k = 0; k < 32; ++k) {
        const float p = sS[m][k];
        #pragma unroll
        for (int j = 0; j < 8; ++j) o[j] += p * sV[k][c0 + j];
    }
    #pragma unroll
    for (int j = 0; j < 8; ++j)
        out[((size_t)(b * 32 + m)) * Dc + h * HDc + c0 + j] = o[j];
}

// ---------------------------------------------------------------- add + layernorm
__global__ __launch_bounds__(256)
void addln_kernel(const float* __restrict__ xa, const float* __restrict__ xb,
                  const float* __restrict__ g, const float* __restrict__ be,
                  float* __restrict__ out) {
    const int row = blockIdx.x;
    const int tid = threadIdx.x;
    __shared__ float red[8];
    float v[3];
    float s = 0.f, sq = 0.f;
    #pragma unroll
    for (int i = 0; i < 3; ++i) {
        const int d = tid + i * 256;
        const float x = xa[(size_t)row * Dc + d] + xb[(size_t)row * Dc + d];
        v[i] = x; s += x; sq += x * x;
    }
    #pragma unroll
    for (int off = 32; off > 0; off >>= 1) {
        s += __shfl_down(s, off);
        sq += __shfl_down(sq, off);
    }
    if ((tid & 63) == 0) { red[tid >> 6] = s; red[4 + (tid >> 6)] = sq; }
    __syncthreads();
    const float ts = red[0] + red[1] + red[2] + red[3];
    const float tq = red[4] + red[5] + red[6] + red[7];
    const float mean = ts * (1.0f / Dc);
    const float var = tq * (1.0f / Dc) - mean * mean;
    const float inv = rsqrtf(var + 1e-5f);
    #pragma unroll
    for (int i = 0; i < 3; ++i) {
        const int d = tid + i * 256;
        out[(size_t)row * Dc + d] = (v[i] - mean) * inv * g[d] + be[d];
    }
}

// ---------------------------------------------------------------- launch
extern "C" void kernel_launch(void* const* d_in, const int* in_sizes, int n_in,
                              void* d_out, int out_size, void* d_ws, size_t ws_size,
                              hipStream_t stream) {
    const float* lhs   = (const float*)d_in[0];
    const float* attnw = (const float*)d_in[1];
    // d_in[2] attn_b: scalar, cancels in softmax
    const float* ipw = (const float*)d_in[3];
    const float* ipb = (const float*)d_in[4];
    const float* oww = (const float*)d_in[5];
    const float* owb = (const float*)d_in[6];
    const float* g1  = (const float*)d_in[7];
    const float* b1  = (const float*)d_in[8];
    const float* l1w = (const float*)d_in[9];
    const float* l1b = (const float*)d_in[10];
    const float* l2w = (const float*)d_in[11];
    const float* l2b = (const float*)d_in[12];
    const float* g2  = (const float*)d_in[13];
    const float* b2  = (const float*)d_in[14];
    const float* cw1 = (const float*)d_in[15];
    const float* cw2 = (const float*)d_in[16];
    const float* cb2 = (const float*)d_in[17];
    const int* pos   = (const int*)d_in[18];
    const int* emask = (const int*)d_in[19];
    float* out = (float*)d_out;

    constexpr size_t N_IP = (size_t)Lc * 3 * Dc * Dc;   // 7,077,888
    constexpr size_t N_OW = (size_t)Lc * Dc * Dc;       // 2,359,296
    constexpr size_t N_L1 = (size_t)Lc * DFFc * Dc;     // 9,437,184
    constexpr size_t N_L2 = (size_t)Lc * Dc * DFFc;     // 9,437,184
    constexpr size_t N_C1 = (size_t)100 * Dc;           // 76,800
    constexpr size_t N_C2 = (size_t)Ec * 100;           // 10,000,000

    // bf16 copies of transformer weights live in the TAIL of d_out (dead before the
    // final GEMM overwrites all of d_out). cls_w2 bf16 + f32 activations live in d_ws.
    const size_t out_bytes = (size_t)out_size * 4;
    const size_t wtail = 2 * (N_IP + N_OW + N_L1 + N_L2 + N_C1);   // 56,776,704 B
    unsigned short* bw_ip = (unsigned short*)((char*)d_out + ((out_bytes - wtail) & ~(size_t)15));
    unsigned short* bw_ow = bw_ip + N_IP;
    unsigned short* bw_l1 = bw_ow + N_OW;
    unsigned short* bw_l2 = bw_l1 + N_L1;
    unsigned short* bw_c1 = bw_l2 + N_L2;

    char* ws = (char*)d_ws;
    unsigned short* bw_c2 = (unsigned short*)ws;          // 20,000,000 B
    float* fbase = (float*)(ws + 2 * N_C2);
    float* xA    = fbase;               // [1024,768]
    float* xB    = xA + (size_t)TOK * Dc;
    float* qkvb  = xB + (size_t)TOK * Dc;    // [1024,2304]
    float* attno = qkvb + (size_t)TOK * 3 * Dc;
    float* bufT  = attno + (size_t)TOK * Dc;
    float* bufH  = bufT + (size_t)TOK * Dc;  // [1024,3072]
    float* bufC  = bufH + (size_t)TOK * DFFc; // [1024,100]

    // weight conversion
    cvt_kernel<<<1024, 256, 0, stream>>>(ipw, bw_ip, (int)(N_IP / 4));
    cvt_kernel<<<1024, 256, 0, stream>>>(oww, bw_ow, (int)(N_OW / 4));
    cvt_kernel<<<1024, 256, 0, stream>>>(l1w, bw_l1, (int)(N_L1 / 4));
    cvt_kernel<<<1024, 256, 0, stream>>>(l2w, bw_l2, (int)(N_L2 / 4));
    cvt_kernel<<<256, 256, 0, stream>>>(cw1, bw_c1, (int)(N_C1 / 4));
    cvt_kernel<<<1024, 256, 0, stream>>>(cw2, bw_c2, (int)(N_C2 / 4));

    // mention pooling -> xA
    pool_kernel<<<TOK, 256, 0, stream>>>(lhs, attnw, pos, emask, xA);

    auto g64 = [&](const float* A, const unsigned short* B, const float* bias, float* C,
                   int N, int K, int relu) {
        dim3 grid((N + 63) / 64, TOK / 64);
        gemm_bf16_kernel<64, 64, 2, 2><<<grid, 256, 0, stream>>>(A, B, bias, C, TOK, N, K, relu);
    };

    for (int l = 0; l < Lc; ++l) {
        g64(xA, bw_ip + (size_t)l * 3 * Dc * Dc, ipb + (size_t)l * 3 * Dc, qkvb, 3 * Dc, Dc, 0);
        attn_kernel<<<Bc * Hc, 256, 0, stream>>>(qkvb, attno);
        g64(attno, bw_ow + (size_t)l * Dc * Dc, owb + (size_t)l * Dc, bufT, Dc, Dc, 0);
        addln_kernel<<<TOK, 256, 0, stream>>>(xA, bufT, g1 + (size_t)l * Dc, b1 + (size_t)l * Dc, xB);
        g64(xB, bw_l1 + (size_t)l * DFFc * Dc, l1b + (size_t)l * DFFc, bufH, DFFc, Dc, 1);
        g64(bufH, bw_l2 + (size_t)l * Dc * DFFc, l2b + (size_t)l * Dc, bufT, Dc, DFFc, 0);
        addln_kernel<<<TOK, 256, 0, stream>>>(xB, bufT, g2 + (size_t)l * Dc, b2 + (size_t)l * Dc, xA);
    }

    // classifier
    g64(xA, bw_c1, nullptr, bufC, 100, Dc, 0);
    {
        dim3 grid((Ec + 127) / 128, TOK / 128);
        gemm_bf16_kernel<128, 128, 4, 4><<<grid, 256, 0, stream>>>(bufC, bw_c2, cb2, out, TOK, Ec, 100, 0);
    }
}